// Round 1
// baseline (216.061 us; speedup 1.0000x reference)
//
#include <hip/hip_runtime.h>
#include <math.h>

#define VAR0 0.1f
#define VAR1 0.2f
#define THRESH 0.5f
#define THETA 0.01f
#define MAXG 128

// ---------------- decode arm boxes ----------------
__global__ void k_decode(const float* __restrict__ arm_loc, const float* __restrict__ priors,
                         float* __restrict__ dec, int B, int P) {
    int i = blockIdx.x * blockDim.x + threadIdx.x;
    int n = B * P;
    if (i >= n) return;
    int p = i % P;
    float lx = arm_loc[(size_t)i*4+0], ly = arm_loc[(size_t)i*4+1];
    float lw = arm_loc[(size_t)i*4+2], lh = arm_loc[(size_t)i*4+3];
    float pcx = priors[p*4+0], pcy = priors[p*4+1], pw = priors[p*4+2], ph = priors[p*4+3];
    float cx = pcx + lx * VAR0 * pw;
    float cy = pcy + ly * VAR0 * ph;
    float w  = pw * expf(lw * VAR1);
    float h  = ph * expf(lh * VAR1);
    float4 o;
    o.x = cx - w * 0.5f;
    o.y = cy - h * 0.5f;
    o.z = cx + w * 0.5f;
    o.w = cy + h * 0.5f;
    ((float4*)dec)[i] = o;
}

// ---------------- per-(b,g): argmax over P of IoU (first-occurrence ties) ----------------
__global__ void k_bestprior(const float* __restrict__ dec, const float* __restrict__ targets,
                            const int* __restrict__ num_gts, int* __restrict__ bpi,
                            int B, int P, int G) {
    int g = blockIdx.x, b = blockIdx.y;
    int tid = threadIdx.x;
    int ng = num_gts[b];
    if (g >= ng) { if (tid == 0) bpi[b*G+g] = -1; return; }
    const float* t = targets + ((size_t)b*G + g) * 5;
    float t0=t[0], t1=t[1], t2=t[2], t3=t[3];
    float areaA = (t2 - t0) * (t3 - t1);
    const float4* db = ((const float4*)dec) + (size_t)b*P;
    float best = -1.0f; int bidx = P;
    for (int p = tid; p < P; p += blockDim.x) {
        float4 d = db[p];
        float lt0 = fmaxf(t0, d.x), lt1 = fmaxf(t1, d.y);
        float rb0 = fminf(t2, d.z), rb1 = fminf(t3, d.w);
        float w = rb0 - lt0; if (w < 0.f) w = 0.f;
        float h = rb1 - lt1; if (h < 0.f) h = 0.f;
        float inter = w * h;
        float areaB = (d.z - d.x) * (d.w - d.y);
        float ov = inter / (areaA + areaB - inter);
        if (ov > best) { best = ov; bidx = p; }   // strict > keeps first occurrence in stream
    }
    __shared__ float sv[256];
    __shared__ int   si[256];
    sv[tid] = best; si[tid] = bidx;
    __syncthreads();
    for (int off = 128; off > 0; off >>= 1) {
        if (tid < off) {
            float v2 = sv[tid+off]; int i2 = si[tid+off];
            if (v2 > sv[tid] || (v2 == sv[tid] && i2 < si[tid])) { sv[tid] = v2; si[tid] = i2; }
        }
        __syncthreads();
    }
    if (tid == 0) bpi[b*G+g] = si[0];
}

// ---------------- per-(b,p): best-truth, forced match, encode+smoothL1, lse/ce ----------------
__global__ void k_match(const float* __restrict__ dec, const float* __restrict__ arm_conf,
                        const float* __restrict__ odm_loc, const float* __restrict__ odm_conf,
                        const float* __restrict__ targets, const int* __restrict__ num_gts,
                        const int* __restrict__ bpi,
                        float* __restrict__ lc, float* __restrict__ ce,
                        unsigned char* __restrict__ posm,
                        float* __restrict__ partL, int* __restrict__ npos,
                        int B, int P, int C, int G) {
    int b = blockIdx.y;
    int p = blockIdx.x * blockDim.x + threadIdx.x;
    int tid = threadIdx.x;
    __shared__ float st[MAXG*5];
    __shared__ int   sbpi[MAXG];
    __shared__ int   sng;
    if (tid == 0) sng = num_gts[b];
    for (int i = tid; i < G*5; i += blockDim.x) st[i] = targets[(size_t)b*G*5 + i];
    for (int i = tid; i < G;   i += blockDim.x) sbpi[i] = bpi[b*G + i];
    __syncthreads();
    int ng = sng;
    float lsum = 0.f; int pcount = 0;
    if (p < P) {
        size_t i = (size_t)b*P + p;
        float4 d = ((const float4*)dec)[i];
        float areaB = (d.z - d.x) * (d.w - d.y);
        float bov = -2.0f; int bidx = 0;
        for (int g = 0; g < ng; ++g) {
            float t0=st[g*5], t1=st[g*5+1], t2=st[g*5+2], t3=st[g*5+3];
            float lt0 = fmaxf(t0, d.x), lt1 = fmaxf(t1, d.y);
            float rb0 = fminf(t2, d.z), rb1 = fminf(t3, d.w);
            float w = rb0 - lt0; if (w < 0.f) w = 0.f;
            float h = rb1 - lt1; if (h < 0.f) h = 0.f;
            float inter = w * h;
            float areaA = (t2 - t0) * (t3 - t1);
            float ov = inter / (areaA + areaB - inter);
            if (ov > bov) { bov = ov; bidx = g; }  // first occurrence of max
        }
        // forced matches: ascending g, last-wins (matches CPU scatter semantics)
        for (int g = 0; g < ng; ++g) if (sbpi[g] == p) { bov = 2.0f; bidx = g; }
        int conf_t = (bov < THRESH) ? 0 : (int)st[bidx*5+4];
        // p_obj = softmax(arm_conf)[...,1]
        float c0 = arm_conf[i*2], c1 = arm_conf[i*2+1];
        float mm = fmaxf(c0, c1);
        float e0 = expf(c0 - mm), e1 = expf(c1 - mm);
        float p_obj = e1 / (e0 + e1);
        bool pos = (conf_t > 0) && (p_obj > THETA);
        if (pos) {
            pcount = 1;
            float pcx = (d.x + d.z) * 0.5f, pcy = (d.y + d.w) * 0.5f;
            float pw = d.z - d.x, ph = d.w - d.y;
            float t0=st[bidx*5], t1=st[bidx*5+1], t2=st[bidx*5+2], t3=st[bidx*5+3];
            float g0 = ((t0 + t2) * 0.5f - pcx) / (VAR0 * pw);
            float g1 = ((t1 + t3) * 0.5f - pcy) / (VAR0 * ph);
            float g2 = logf((t2 - t0) / pw) / VAR1;
            float g3 = logf((t3 - t1) / ph) / VAR1;
            const float* ol = odm_loc + i*4;
            float dd;
            dd = fabsf(ol[0] - g0); lsum += (dd < 1.f) ? 0.5f*dd*dd : dd - 0.5f;
            dd = fabsf(ol[1] - g1); lsum += (dd < 1.f) ? 0.5f*dd*dd : dd - 0.5f;
            dd = fabsf(ol[2] - g2); lsum += (dd < 1.f) ? 0.5f*dd*dd : dd - 0.5f;
            dd = fabsf(ol[3] - g3); lsum += (dd < 1.f) ? 0.5f*dd*dd : dd - 0.5f;
        }
        // logsumexp over C classes
        const float* oc = odm_conf + i * (size_t)C;
        float mx = oc[0];
        for (int j = 1; j < C; ++j) mx = fmaxf(mx, oc[j]);
        float sume = 0.f;
        for (int j = 0; j < C; ++j) sume += expf(oc[j] - mx);
        float lse = mx + logf(sume);
        float cev = lse - oc[conf_t];   // >= 0 always
        ce[i] = cev;
        lc[i] = pos ? 0.f : cev;
        posm[i] = pos ? 1 : 0;
    }
    // block reduce loss_l partial + pos count
    __shared__ float rl[256];
    __shared__ int   rc[256];
    rl[tid] = lsum; rc[tid] = pcount;
    __syncthreads();
    for (int off = 128; off > 0; off >>= 1) {
        if (tid < off) { rl[tid] += rl[tid+off]; rc[tid] += rc[tid+off]; }
        __syncthreads();
    }
    if (tid == 0) {
        partL[b * gridDim.x + blockIdx.x] = rl[0];
        if (rc[0]) atomicAdd(&npos[b], rc[0]);
    }
}

// ---------------- per-batch: radix-select Kth-largest lc, tie-break by index, sum masked ce ----------------
__global__ void k_select_lossc(const float* __restrict__ lc, const float* __restrict__ ce,
                               const unsigned char* __restrict__ posm,
                               const int* __restrict__ npos,
                               float* __restrict__ partC, int B, int P) {
    int b = blockIdx.x;
    int tid = threadIdx.x;
    int nt = blockDim.x;
    const unsigned* lcb = (const unsigned*)lc + (size_t)b*P;   // lc >= 0 -> bits monotone
    __shared__ unsigned hist[256];
    __shared__ unsigned sh_prefix;
    __shared__ int sh_k;
    if (tid == 0) {
        int np = npos[b];
        int K = 3 * np;
        int pm1 = P - 1;
        if (K > pm1) K = pm1;
        sh_k = K; sh_prefix = 0u;
    }
    __syncthreads();
    int K0 = sh_k;
    unsigned T; int krem;
    if (K0 <= 0) { T = 0xFFFFFFFFu; krem = 0; }
    else {
        for (int pass = 0; pass < 4; ++pass) {
            int shift = 24 - 8*pass;
            for (int i = tid; i < 256; i += nt) hist[i] = 0u;
            __syncthreads();
            unsigned pref = sh_prefix;
            for (int p = tid; p < P; p += nt) {
                unsigned v = lcb[p];
                bool ok = (pass == 0) || ((v >> (shift+8)) == (pref >> (shift+8)));
                if (ok) atomicAdd(&hist[(v >> shift) & 255u], 1u);
            }
            __syncthreads();
            if (tid == 0) {
                int k = sh_k; unsigned pr = sh_prefix;
                for (int bin = 255; bin >= 0; --bin) {
                    int c = (int)hist[bin];
                    if (k <= c) { pr |= ((unsigned)bin) << shift; break; }
                    k -= c;
                }
                sh_k = k; sh_prefix = pr;
            }
            __syncthreads();
        }
        T = sh_prefix; krem = sh_k;
    }
    // ordered pass: equals tie-break by ascending index (stable-sort semantics) + ce sum
    __shared__ int scanbuf[1024];
    __shared__ int sh_base;
    if (tid == 0) sh_base = 0;
    __syncthreads();
    float csum = 0.f;
    const float* ceb = ce + (size_t)b*P;
    const unsigned char* pmb = posm + (size_t)b*P;
    for (int start = 0; start < P; start += nt) {
        int p = start + tid;
        int eq = 0; bool gt = false; bool ps = false; float cv = 0.f;
        if (p < P) {
            unsigned v = lcb[p];
            gt = (v > T);
            eq = (v == T) ? 1 : 0;
            ps = pmb[p] != 0;
            cv = ceb[p];
        }
        scanbuf[tid] = eq;
        __syncthreads();
        for (int off = 1; off < nt; off <<= 1) {
            int tmp = (tid >= off) ? scanbuf[tid - off] : 0;
            __syncthreads();
            scanbuf[tid] += tmp;
            __syncthreads();
        }
        int incl  = scanbuf[tid];
        int base  = sh_base;
        int total = scanbuf[nt - 1];
        __syncthreads();
        if (p < P) {
            bool sel_eq = eq && ((base + incl - 1) < krem);
            bool mask = ps || gt || sel_eq;
            if (mask) csum += cv;
        }
        if (tid == 0) sh_base = base + total;
        __syncthreads();
    }
    __shared__ float rs[1024];
    rs[tid] = csum;
    __syncthreads();
    for (int off = nt >> 1; off > 0; off >>= 1) {
        if (tid < off) rs[tid] += rs[tid + off];
        __syncthreads();
    }
    if (tid == 0) partC[b] = rs[0];
}

// ---------------- final deterministic reduce + divide ----------------
__global__ void k_final(const float* __restrict__ partL, const float* __restrict__ partC,
                        const int* __restrict__ npos, int nPart, int B,
                        float* __restrict__ out) {
    __shared__ float sL[256];
    __shared__ float sC[256];
    __shared__ int   sN[256];
    int tid = threadIdx.x;
    float aL = 0.f, aC = 0.f; int aN = 0;
    for (int i = tid; i < nPart; i += 256) aL += partL[i];
    for (int i = tid; i < B;     i += 256) { aC += partC[i]; aN += npos[i]; }
    sL[tid] = aL; sC[tid] = aC; sN[tid] = aN;
    __syncthreads();
    for (int off = 128; off > 0; off >>= 1) {
        if (tid < off) { sL[tid] += sL[tid+off]; sC[tid] += sC[tid+off]; sN[tid] += sN[tid+off]; }
        __syncthreads();
    }
    if (tid == 0) {
        float N = (float)sN[0];
        out[0] = sL[0] / N;
        out[1] = sC[0] / N;
    }
}

extern "C" void kernel_launch(void* const* d_in, const int* in_sizes, int n_in,
                              void* d_out, int out_size, void* d_ws, size_t ws_size,
                              hipStream_t stream) {
    const float* arm_loc  = (const float*)d_in[0];
    const float* arm_conf = (const float*)d_in[1];
    const float* odm_loc  = (const float*)d_in[2];
    const float* odm_conf = (const float*)d_in[3];
    const float* priors   = (const float*)d_in[4];
    const float* targets  = (const float*)d_in[5];
    const int*   num_gts  = (const int*)d_in[6];
    float* out = (float*)d_out;

    int B = in_sizes[6];
    int P = in_sizes[4] / 4;
    int C = in_sizes[3] / (B * P);
    int G = in_sizes[5] / (B * 5);

    char* ws = (char*)d_ws;
    size_t off = 0;
    auto alloc = [&](size_t bytes) -> void* {
        void* ptr = ws + off;
        off = (off + bytes + 255) & ~(size_t)255;
        return ptr;
    };
    float* dec   = (float*)alloc((size_t)B * P * 4 * sizeof(float));
    float* lc    = (float*)alloc((size_t)B * P * sizeof(float));
    float* ce    = (float*)alloc((size_t)B * P * sizeof(float));
    unsigned char* posm = (unsigned char*)alloc((size_t)B * P);
    int* bpi     = (int*)alloc((size_t)B * G * sizeof(int));
    int* npos    = (int*)alloc((size_t)B * sizeof(int));
    int NBX = (P + 255) / 256;
    float* partL = (float*)alloc((size_t)B * NBX * sizeof(float));
    float* partC = (float*)alloc((size_t)B * sizeof(float));

    hipMemsetAsync(npos, 0, (size_t)B * sizeof(int), stream);

    int nBP = B * P;
    k_decode<<<(nBP + 255) / 256, 256, 0, stream>>>(arm_loc, priors, dec, B, P);
    k_bestprior<<<dim3(G, B), 256, 0, stream>>>(dec, targets, num_gts, bpi, B, P, G);
    k_match<<<dim3(NBX, B), 256, 0, stream>>>(dec, arm_conf, odm_loc, odm_conf, targets, num_gts,
                                              bpi, lc, ce, posm, partL, npos, B, P, C, G);
    k_select_lossc<<<B, 1024, 0, stream>>>(lc, ce, posm, npos, partC, B, P);
    k_final<<<1, 256, 0, stream>>>(partL, partC, npos, B * NBX, B, out);
}